// Round 12
// baseline (180.909 us; speedup 1.0000x reference)
//
#include <hip/hip_runtime.h>
#include <hip/hip_bf16.h>

#define T_TOK 8192
#define DDIM 1024
#define HDIM 1024
#define NEXP 8
#define KTOP 2
#define NROWS (T_TOK * KTOP)

typedef __attribute__((ext_vector_type(8))) short bf16x8;
typedef __attribute__((ext_vector_type(4))) float f32x4;

__device__ __forceinline__ unsigned short f2bf(float f) {
    unsigned u = __builtin_bit_cast(unsigned, f);
    u += 0x7fffu + ((u >> 16) & 1u);   // RNE
    return (unsigned short)(u >> 16);
}
__device__ __forceinline__ float bf2f(unsigned short h) {
    return __builtin_bit_cast(float, (unsigned)h << 16);
}

// async global->LDS, 16B per lane; LDS dest wave-uniform base + lane*16.
__device__ __forceinline__ void gll16(const unsigned short* g, const unsigned short* l) {
    __builtin_amdgcn_global_load_lds(
        (const __attribute__((address_space(1))) unsigned int*)g,
        (__attribute__((address_space(3))) unsigned int*)l, 16, 0, 0);
}

// ---------------- prep kernels ----------------

__global__ __launch_bounds__(256) void cvt_bf16_k(const float* __restrict__ in,
                                                  unsigned short* __restrict__ out, int n4) {
    int i = blockIdx.x * 256 + threadIdx.x;
    if (i >= n4) return;
    float4 v = ((const float4*)in)[i];
    ushort4 o;
    o.x = f2bf(v.x); o.y = f2bf(v.y); o.z = f2bf(v.z); o.w = f2bf(v.w);
    ((ushort4*)out)[i] = o;
}

// in: [nmat][R][C] f32  ->  out: [nmat][C][R] bf16
__global__ __launch_bounds__(256) void transpose_cast_k(const float* __restrict__ in,
                                                        unsigned short* __restrict__ out,
                                                        int R, int C) {
    __shared__ unsigned short tile[32][33];
    int m = blockIdx.z;
    const float* src = in + (size_t)m * R * C;
    unsigned short* dst = out + (size_t)m * R * C;
    int c0 = blockIdx.x * 32, r0 = blockIdx.y * 32;
    int tx = threadIdx.x & 31, ty = threadIdx.x >> 5;
#pragma unroll
    for (int i = 0; i < 32; i += 8)
        tile[ty + i][tx] = f2bf(src[(size_t)(r0 + ty + i) * C + c0 + tx]);
    __syncthreads();
#pragma unroll
    for (int i = 0; i < 32; i += 8)
        dst[(size_t)(c0 + ty + i) * R + r0 + tx] = tile[tx][ty + i];
}

// --------- CONTROL: 256x256 GEMM, (qm,k-slice) phasing (r11, verified) ----------
constexpr int BM2 = 256, BN2 = 256, BK2 = 64;
constexpr int NT2 = DDIM / BK2;   // 16 K-tiles

template <int VARIANT>
__global__ __launch_bounds__(512) void gemm256_ks_k(
    const unsigned short* __restrict__ A, const int* __restrict__ rowidx, int lda,
    const unsigned short* __restrict__ Bt, const float* __restrict__ biasE,
    const unsigned short* __restrict__ Gin, unsigned short* __restrict__ Out,
    const int* __restrict__ offsets, int N, int K) {
    __shared__ __attribute__((aligned(16))) unsigned short lds[65536];  // 128 KiB

    const int nbn = N / BN2;                          // 4
    int l = (blockIdx.x & 7) * 32 + (blockIdx.x >> 3);
    int brow = l / nbn, bcol = l % nbn;
    int row0 = brow * BM2, col0 = bcol * BN2;
    int e = 0;
    while (offsets[e + 1] <= row0) ++e;

    const unsigned short* Bte = Bt + (size_t)e * N * K;
    const float* bias = biasE + (size_t)e * N;

    int tid = threadIdx.x;
    int lane = tid & 63, wid = tid >> 6;
    int wm = wid >> 2, wn = wid & 3;                  // 2x4 wave grid
    int l15 = lane & 15, l4 = lane >> 4;

    int srow = lane >> 3;
    int c8 = ((lane & 7) ^ srow) * 8;
    const unsigned short* aS[2][2];
    const unsigned short* bS[2][2];
#pragma unroll
    for (int h = 0; h < 2; ++h)
#pragma unroll
        for (int q = 0; q < 2; ++q) {
            int r = (wid & 3) * 16 + q * 8 + srow + h * 64 + (wid >> 2) * 128;
            int ar = rowidx ? rowidx[row0 + r] : row0 + r;
            aS[h][q] = A + (size_t)ar * lda + c8;
            int cc = (wid & 1) * 16 + q * 8 + srow + h * 32 + (wid >> 1) * 64;
            bS[h][q] = Bte + (size_t)(col0 + cc) * K + c8;
        }
    unsigned wq = wid * 1024;

#define STG_A(BUF, H, T) { \
        gll16(aS[H][0] + (T) * BK2, lds + (BUF) * 16384 + (H) * 8192 + wq);       \
        gll16(aS[H][1] + (T) * BK2, lds + (BUF) * 16384 + (H) * 8192 + wq + 512); }
#define STG_B(BUF, H, T) { \
        gll16(bS[H][0] + (T) * BK2, lds + 32768 + (BUF) * 16384 + (H) * 8192 + wq);       \
        gll16(bS[H][1] + (T) * BK2, lds + 32768 + (BUF) * 16384 + (H) * 8192 + wq + 512); }

    const char* LB = (const char*)lds;
    int arow = (wm * 64 + l15) * 128;
    int brw = (wn * 32 + l15) * 128;
    int cx = l15 & 7;
    int ch0 = (l4 ^ cx) * 16;
    int ch1 = ((4 + l4) ^ cx) * 16;

    f32x4 acc[8][4] = {};
    bf16x8 fa[4], fb0[4], fb1[4];

#define RD_FA(BUF, QM, CH) {                                                  \
        const char* Ab_ = LB + (BUF) * 32768 + (QM) * 16384 + arow;           \
        fa[0] = *(const bf16x8*)(Ab_ + 0 * 2048 + (CH));                      \
        fa[1] = *(const bf16x8*)(Ab_ + 1 * 2048 + (CH));                      \
        fa[2] = *(const bf16x8*)(Ab_ + 2 * 2048 + (CH));                      \
        fa[3] = *(const bf16x8*)(Ab_ + 3 * 2048 + (CH)); }
#define RD_FB(BUF, FB, CH) {                                                  \
        const char* Bb_ = LB + 65536 + (BUF) * 32768 + brw;                   \
        FB[0] = *(const bf16x8*)(Bb_ + (CH));                                 \
        FB[1] = *(const bf16x8*)(Bb_ + 2048 + (CH));                          \
        FB[2] = *(const bf16x8*)(Bb_ + 16384 + (CH));                         \
        FB[3] = *(const bf16x8*)(Bb_ + 16384 + 2048 + (CH)); }
#define MFMA16(QM, FB)                                                        \
    asm volatile("s_waitcnt lgkmcnt(0)" ::: "memory");                        \
    __builtin_amdgcn_sched_barrier(0);                                        \
    __builtin_amdgcn_s_setprio(1);                                            \
    _Pragma("unroll") for (int mi = 0; mi < 4; ++mi)                          \
    _Pragma("unroll") for (int ni = 0; ni < 4; ++ni)                          \
        acc[(QM) * 4 + mi][ni] = __builtin_amdgcn_mfma_f32_16x16x32_bf16(     \
            fa[mi], FB[ni], acc[(QM) * 4 + mi][ni], 0, 0, 0);                 \
    __builtin_amdgcn_s_setprio(0);

    STG_A(0, 0, 0) STG_A(0, 1, 0) STG_B(0, 0, 0) STG_B(0, 1, 0)
    STG_A(1, 0, 1) STG_B(1, 0, 1) STG_B(1, 1, 1)
    asm volatile("s_waitcnt vmcnt(6)" ::: "memory");
    __builtin_amdgcn_s_barrier();

#pragma unroll 1
    for (int t = 0; t < NT2; ++t) {
        int bc = t & 1, bo = bc ^ 1;
        RD_FA(bc, 0, ch0)
        RD_FB(bc, fb0, ch0)
        if (t + 1 < NT2) STG_A(bo, 1, t + 1)
        MFMA16(0, fb0)
        __builtin_amdgcn_s_barrier();
        RD_FA(bc, 0, ch1)
        RD_FB(bc, fb1, ch1)
        MFMA16(0, fb1)
        __builtin_amdgcn_s_barrier();
        RD_FA(bc, 1, ch0)
        if (t + 2 < NT2) { STG_A(bc, 0, t + 2) STG_B(bc, 0, t + 2) }
        MFMA16(1, fb0)
        __builtin_amdgcn_s_barrier();
        RD_FA(bc, 1, ch1)
        if (t + 2 < NT2) STG_B(bc, 1, t + 2)
        MFMA16(1, fb1)
        if (t + 1 < NT2) {
            if (t + 2 < NT2) { asm volatile("s_waitcnt vmcnt(6)" ::: "memory"); }
            else             { asm volatile("s_waitcnt vmcnt(0)" ::: "memory"); }
            __builtin_amdgcn_s_barrier();
        }
    }
#undef MFMA16
#undef RD_FB
#undef RD_FA
#undef STG_B
#undef STG_A

    float bv[4];
#pragma unroll
    for (int ni = 0; ni < 4; ++ni)
        bv[ni] = bias[col0 + wn * 64 + ni * 16 + l15];

#pragma unroll
    for (int mi = 0; mi < 8; ++mi) {
        int orow_b = row0 + wm * 128 + mi * 16 + l4 * 4;
#pragma unroll
        for (int ni = 0; ni < 4; ++ni) {
            int ocol = col0 + wn * 64 + ni * 16 + l15;
#pragma unroll
            for (int q = 0; q < 4; ++q) {
                size_t oidx = (size_t)(orow_b + q) * N + ocol;
                float v = acc[mi][ni][q] + bv[ni];
                if (VARIANT == 1) {
                    float g = bf2f(Gin[oidx]);
                    float s = g / (1.0f + __expf(-g));
                    v = s * v;
                }
                Out[oidx] = f2bf(v);
            }
        }
    }
}

// --------- TEST: 128x128 m97-replica, single-buffer, 3-4 blocks/CU (block-TLP) --
// 4 waves (2x2), per-wave 64x64 out, BK=64, 32KB LDS single buffer.
// Per iter: 8 gll16 -> __syncthreads (compiler drains vmcnt+lgkm; OTHER BLOCKS
// run during the wait - the TLP hypothesis) -> 16 ds_read + 32 MFMA
// (compiler fine-schedules lgkmcnt) -> __syncthreads -> next.
// Swizzle identical to control (pre-swizzled src + XOR reads, 0 conflicts).
constexpr int BMy = 128, BNy = 128, BKy = 64;

__global__ __launch_bounds__(256, 3) void gemm128_tlp_k(
    const unsigned short* __restrict__ A, int lda,
    const unsigned short* __restrict__ Bt, const float* __restrict__ biasE,
    unsigned short* __restrict__ Out, const int* __restrict__ offsets,
    int N, int K) {
    __shared__ __attribute__((aligned(16))) unsigned short lds[16384];  // 32 KiB

    const int nbn = N / BNy;                          // 8
    int l = (blockIdx.x & 7) * 128 + (blockIdx.x >> 3);
    int brow = l / nbn, bcol = l % nbn;
    int row0 = brow * BMy, col0 = bcol * BNy;
    int e = 0;
    while (offsets[e + 1] <= row0) ++e;

    const unsigned short* Bte = Bt + (size_t)e * N * K;
    const float* bias = biasE + (size_t)e * N;

    int tid = threadIdx.x;
    int lane = tid & 63, wid = tid >> 6;
    int wr = wid >> 1, wc = wid & 1;                  // 2x2 wave grid
    int l15 = lane & 15, l4 = lane >> 4;

    // staging: 16 A-groups + 16 B-groups of 1KB (8 rows x 128B); wave w owns
    // A groups [w*4,+4) and B groups [w*4,+4). Inverse-swizzled source.
    int srow = lane >> 3;
    int c8 = ((lane & 7) ^ srow) * 8;
    const unsigned short* aS[4];
    const unsigned short* bS[4];
#pragma unroll
    for (int q = 0; q < 4; ++q) {
        int g = wid * 4 + q;
        aS[q] = A + (size_t)(row0 + g * 8 + srow) * lda + c8;
        bS[q] = Bte + (size_t)(col0 + g * 8 + srow) * K + c8;
    }

    // swizzled read offsets
    const char* LB = (const char*)lds;
    int arow = (wr * 64 + l15) * 128;                 // byte, within A tile
    int brw = (wc * 64 + l15) * 128;                  // byte, within B tile
    int cx = l15 & 7;
    int ch0 = (l4 ^ cx) * 16;
    int ch1 = ((4 + l4) ^ cx) * 16;

    f32x4 acc[4][4] = {};

#pragma unroll 1
    for (int t = 0; t < K / BKy; ++t) {
        int k0 = t * BKy;
#pragma unroll
        for (int q = 0; q < 4; ++q) {
            gll16(aS[q] + k0, lds + (wid * 4 + q) * 512);
            gll16(bS[q] + k0, lds + 8192 + (wid * 4 + q) * 512);
        }
        __syncthreads();   // drains vmcnt(0); co-resident blocks hide the wait
        bf16x8 fa[2][4], fb[2][4];
#pragma unroll
        for (int mi = 0; mi < 4; ++mi) {
            fa[0][mi] = *(const bf16x8*)(LB + arow + mi * 2048 + ch0);
            fa[1][mi] = *(const bf16x8*)(LB + arow + mi * 2048 + ch1);
        }
#pragma unroll
        for (int ni = 0; ni < 4; ++ni) {
            fb[0][ni] = *(const bf16x8*)(LB + 16384 + brw + ni * 2048 + ch0);
            fb[1][ni] = *(const bf16x8*)(LB + 16384 + brw + ni * 2048 + ch1);
        }
#pragma unroll
        for (int s = 0; s < 2; ++s)
#pragma unroll
            for (int mi = 0; mi < 4; ++mi)
#pragma unroll
                for (int ni = 0; ni < 4; ++ni)
                    acc[mi][ni] = __builtin_amdgcn_mfma_f32_16x16x32_bf16(
                        fa[s][mi], fb[s][ni], acc[mi][ni], 0, 0, 0);
        __syncthreads();   // reads done before next stage overwrites
    }

    float bv[4];
#pragma unroll
    for (int ni = 0; ni < 4; ++ni)
        bv[ni] = bias[col0 + wc * 64 + ni * 16 + l15];

#pragma unroll
    for (int mi = 0; mi < 4; ++mi) {
        int orow_b = row0 + wr * 64 + mi * 16 + l4 * 4;
#pragma unroll
        for (int ni = 0; ni < 4; ++ni) {
            int ocol = col0 + wc * 64 + ni * 16 + l15;
#pragma unroll
            for (int q = 0; q < 4; ++q)
                Out[(size_t)(orow_b + q) * N + ocol] = f2bf(acc[mi][ni][q] + bv[ni]);
        }
    }
}

// ---------------- combine ----------------

__global__ __launch_bounds__(256) void combine_k(
    const unsigned short* __restrict__ Y, const int* __restrict__ rev,
    const float* __restrict__ gates, const int* __restrict__ gidx,
    float* __restrict__ out) {
    int t = blockIdx.x;
    int r0 = rev[2 * t], r1 = rev[2 * t + 1];
    float g0 = gates[gidx[2 * t]], g1 = gates[gidx[2 * t + 1]];
    const unsigned short* y0 = Y + (size_t)r0 * DDIM;
    const unsigned short* y1 = Y + (size_t)r1 * DDIM;
    int d = threadIdx.x * 4;
    ushort4 a = *(const ushort4*)(y0 + d);
    ushort4 b = *(const ushort4*)(y1 + d);
    float4 r;
    r.x = g0 * bf2f(a.x) + g1 * bf2f(b.x);
    r.y = g0 * bf2f(a.y) + g1 * bf2f(b.y);
    r.z = g0 * bf2f(a.z) + g1 * bf2f(b.z);
    r.w = g0 * bf2f(a.w) + g1 * bf2f(b.w);
    *(float4*)(out + (size_t)t * DDIM + d) = r;
}

// ---------------- launch ----------------

extern "C" void kernel_launch(void* const* d_in, const int* in_sizes, int n_in,
                              void* d_out, int out_size, void* d_ws, size_t ws_size,
                              hipStream_t stream) {
    const int* offsets = (const int*)d_in[0];
    const float* jagged = (const float*)d_in[1];
    const float* weight = (const float*)d_in[2];
    const float* bias = (const float*)d_in[3];
    const int* index = (const int*)d_in[4];
    const float* weight_p = (const float*)d_in[5];
    const float* weight_out = (const float*)d_in[6];
    const int* rev = (const int*)d_in[7];
    const float* gates = (const float*)d_in[8];
    const int* gidx = (const int*)d_in[9];
    const float* bias_p = (const float*)d_in[10];
    const float* bias_out = (const float*)d_in[11];
    float* out = (float*)d_out;

    char* w = (char*)d_ws;
    unsigned short* jag_bf = (unsigned short*)w; w += (size_t)T_TOK * DDIM * 2;       // 16MB
    unsigned short* W1t    = (unsigned short*)w; w += (size_t)NEXP * DDIM * HDIM * 2; // 16MB
    unsigned short* Wpt    = (unsigned short*)w; w += (size_t)NEXP * DDIM * HDIM * 2; // 16MB
    unsigned short* Wot    = (unsigned short*)w; w += (size_t)NEXP * HDIM * DDIM * 2; // 16MB
    unsigned short* g_ws   = (unsigned short*)w; w += (size_t)NROWS * HDIM * 2;       // 32MB
    unsigned short* h_ws   = (unsigned short*)w; w += (size_t)NROWS * HDIM * 2;       // 32MB
    unsigned short* y_ws   = g_ws;   // g dead after u-GEMM epilogue; reuse for y

    // prep: bf16 cast + weight transposes (B^T layout)
    cvt_bf16_k<<<(T_TOK * DDIM / 4 + 255) / 256, 256, 0, stream>>>(jagged, jag_bf, T_TOK * DDIM / 4);
    transpose_cast_k<<<dim3(HDIM / 32, DDIM / 32, NEXP), 256, 0, stream>>>(weight, W1t, DDIM, HDIM);
    transpose_cast_k<<<dim3(HDIM / 32, DDIM / 32, NEXP), 256, 0, stream>>>(weight_p, Wpt, DDIM, HDIM);
    transpose_cast_k<<<dim3(DDIM / 32, HDIM / 32, NEXP), 256, 0, stream>>>(weight_out, Wot, HDIM, DDIM);

    const int grid256 = (NROWS / BM2) * (HDIM / BN2);   // 256 blocks

    // g = gather(x) @ W + b        [CONTROL r11]
    gemm256_ks_k<0><<<grid256, 512, 0, stream>>>(jag_bf, index, DDIM, W1t, bias, nullptr, g_ws,
                                                 offsets, HDIM, DDIM);
    // h = silu(g) * (gather(x) @ Wp + bp)   [CONTROL r11]
    gemm256_ks_k<1><<<grid256, 512, 0, stream>>>(jag_bf, index, DDIM, Wpt, bias_p, g_ws, h_ws,
                                                 offsets, HDIM, DDIM);
    // y = h @ Wout + bout          [TEST: m97-replica block-TLP]
    const int grid128 = (NROWS / BMy) * (DDIM / BNy);   // 1024 blocks
    gemm128_tlp_k<<<grid128, 256, 0, stream>>>(h_ws, HDIM, Wot, bias_out, y_ws,
                                               offsets, DDIM, HDIM);
    // out[t] = sum_k gates[gidx[t,k]] * y[rev[t,k]]
    combine_k<<<T_TOK, 256, 0, stream>>>(y_ws, rev, gates, gidx, out);
}

// Round 13
// 180.069 us; speedup vs baseline: 1.0047x; 1.0047x over previous
//
#include <hip/hip_runtime.h>
#include <hip/hip_bf16.h>

#define T_TOK 8192
#define DDIM 1024
#define HDIM 1024
#define NEXP 8
#define KTOP 2
#define NROWS (T_TOK * KTOP)

typedef __attribute__((ext_vector_type(8))) short bf16x8;
typedef __attribute__((ext_vector_type(4))) float f32x4;

__device__ __forceinline__ unsigned short f2bf(float f) {
    unsigned u = __builtin_bit_cast(unsigned, f);
    u += 0x7fffu + ((u >> 16) & 1u);   // RNE
    return (unsigned short)(u >> 16);
}
__device__ __forceinline__ float bf2f(unsigned short h) {
    return __builtin_bit_cast(float, (unsigned)h << 16);
}

// async global->LDS, 16B per lane; LDS dest wave-uniform base + lane*16.
__device__ __forceinline__ void gll16(const unsigned short* g, const unsigned short* l) {
    __builtin_amdgcn_global_load_lds(
        (const __attribute__((address_space(1))) unsigned int*)g,
        (__attribute__((address_space(3))) unsigned int*)l, 16, 0, 0);
}

// ---------------- prep kernels ----------------

__global__ __launch_bounds__(256) void cvt_bf16_k(const float* __restrict__ in,
                                                  unsigned short* __restrict__ out, int n4) {
    int i = blockIdx.x * 256 + threadIdx.x;
    if (i >= n4) return;
    float4 v = ((const float4*)in)[i];
    ushort4 o;
    o.x = f2bf(v.x); o.y = f2bf(v.y); o.z = f2bf(v.z); o.w = f2bf(v.w);
    ((ushort4*)out)[i] = o;
}

// in: [nmat][R][C] f32  ->  out: [nmat][C][R] bf16
__global__ __launch_bounds__(256) void transpose_cast_k(const float* __restrict__ in,
                                                        unsigned short* __restrict__ out,
                                                        int R, int C) {
    __shared__ unsigned short tile[32][33];
    int m = blockIdx.z;
    const float* src = in + (size_t)m * R * C;
    unsigned short* dst = out + (size_t)m * R * C;
    int c0 = blockIdx.x * 32, r0 = blockIdx.y * 32;
    int tx = threadIdx.x & 31, ty = threadIdx.x >> 5;
#pragma unroll
    for (int i = 0; i < 32; i += 8)
        tile[ty + i][tx] = f2bf(src[(size_t)(r0 + ty + i) * C + c0 + tx]);
    __syncthreads();
#pragma unroll
    for (int i = 0; i < 32; i += 8)
        dst[(size_t)(c0 + ty + i) * R + r0 + tx] = tile[tx][ty + i];
}

// --------- 128x128 GEMM, m97-structure, single-buffer, 3 blocks/CU (block-TLP) --
// C = act(A @ Bt^T + bias). 256 thr = 4 waves (2x2), per-wave 64x64 out.
// BK=64, 16 K-iters, 32KB LDS single buffer, plain __syncthreads (compiler
// drains vmcnt/lgkm). Block-level TLP (3 blocks/CU, m114) hides the per-tile
// drain: while this block waits, co-resident blocks issue MFMA. This measured
// faster (<48.1us, r12 A/B) than all deep-pipelined 1-block/CU 256x256
// variants (49-52us, r5-r11) and the 2-block/CU deep 128x128 (58.5us, r6).
// Swizzle: 16B chunk c of row r (128B line) stored at phys c^(r&7); gll16
// writes linear from inverse-swizzled global src; reads XOR the same
// (rule 21c) -> ~0 conflicts (involution verified r5-r12).
// T1: XCD-chunked map: 1024 blocks, XCD x owns brows [x*16,+16) = expert x.
// VARIANT 0: out = acc + bias ;  VARIANT 1: out = silu(Gin) * (acc + bias)

constexpr int BMk = 128, BNk = 128, BKk = 64;

template <int VARIANT>
__global__ __launch_bounds__(256, 3) void gemm128_k(
    const unsigned short* __restrict__ A, const int* __restrict__ rowidx, int lda,
    const unsigned short* __restrict__ Bt, const float* __restrict__ biasE,
    const unsigned short* __restrict__ Gin, unsigned short* __restrict__ Out,
    const int* __restrict__ offsets, int N, int K) {
    __shared__ __attribute__((aligned(16))) unsigned short lds[16384];  // 32 KiB

    const int nbn = N / BNk;                          // 8
    int l = (blockIdx.x & 7) * 128 + (blockIdx.x >> 3);
    int brow = l / nbn, bcol = l % nbn;
    int row0 = brow * BMk, col0 = bcol * BNk;
    int e = 0;
    while (offsets[e + 1] <= row0) ++e;

    const unsigned short* Bte = Bt + (size_t)e * N * K;
    const float* bias = biasE + (size_t)e * N;

    int tid = threadIdx.x;
    int lane = tid & 63, wid = tid >> 6;
    int wr = wid >> 1, wc = wid & 1;                  // 2x2 wave grid
    int l15 = lane & 15, l4 = lane >> 4;

    // staging: 16 A-groups + 16 B-groups of 1KB (8 rows x 128B); wave w owns
    // groups [w*4, +4). Inverse-swizzled per-lane global source.
    int srow = lane >> 3;
    int c8 = ((lane & 7) ^ srow) * 8;
    const unsigned short* aS[4];
    const unsigned short* bS[4];
#pragma unroll
    for (int q = 0; q < 4; ++q) {
        int g = wid * 4 + q;
        int gr = row0 + g * 8 + srow;
        int ar = rowidx ? rowidx[gr] : gr;
        aS[q] = A + (size_t)ar * lda + c8;
        bS[q] = Bte + (size_t)(col0 + g * 8 + srow) * K + c8;
    }

    // swizzled read offsets
    const char* LB = (const char*)lds;
    int arow = (wr * 64 + l15) * 128;                 // byte, within A tile
    int brw = (wc * 64 + l15) * 128;                  // byte, within B tile
    int cx = l15 & 7;
    int ch0 = (l4 ^ cx) * 16;
    int ch1 = ((4 + l4) ^ cx) * 16;

    f32x4 acc[4][4] = {};

#pragma unroll 1
    for (int t = 0; t < K / BKk; ++t) {
        int k0 = t * BKk;
#pragma unroll
        for (int q = 0; q < 4; ++q) {
            gll16(aS[q] + k0, lds + (wid * 4 + q) * 512);
            gll16(bS[q] + k0, lds + 8192 + (wid * 4 + q) * 512);
        }
        __syncthreads();   // drains vmcnt(0); co-resident blocks hide the wait
        bf16x8 fa[2][4], fb[2][4];
#pragma unroll
        for (int mi = 0; mi < 4; ++mi) {
            fa[0][mi] = *(const bf16x8*)(LB + arow + mi * 2048 + ch0);
            fa[1][mi] = *(const bf16x8*)(LB + arow + mi * 2048 + ch1);
        }
#pragma unroll
        for (int ni = 0; ni < 4; ++ni) {
            fb[0][ni] = *(const bf16x8*)(LB + 16384 + brw + ni * 2048 + ch0);
            fb[1][ni] = *(const bf16x8*)(LB + 16384 + brw + ni * 2048 + ch1);
        }
#pragma unroll
        for (int s = 0; s < 2; ++s)
#pragma unroll
            for (int mi = 0; mi < 4; ++mi)
#pragma unroll
                for (int ni = 0; ni < 4; ++ni)
                    acc[mi][ni] = __builtin_amdgcn_mfma_f32_16x16x32_bf16(
                        fa[s][mi], fb[s][ni], acc[mi][ni], 0, 0, 0);
        __syncthreads();   // reads done before next stage overwrites
    }

    float bv[4];
#pragma unroll
    for (int ni = 0; ni < 4; ++ni)
        bv[ni] = bias[col0 + wc * 64 + ni * 16 + l15];

#pragma unroll
    for (int mi = 0; mi < 4; ++mi) {
        int orow_b = row0 + wr * 64 + mi * 16 + l4 * 4;
#pragma unroll
        for (int ni = 0; ni < 4; ++ni) {
            int ocol = col0 + wc * 64 + ni * 16 + l15;
#pragma unroll
            for (int q = 0; q < 4; ++q) {
                size_t oidx = (size_t)(orow_b + q) * N + ocol;
                float v = acc[mi][ni][q] + bv[ni];
                if (VARIANT == 1) {
                    float g = bf2f(Gin[oidx]);
                    float s = g / (1.0f + __expf(-g));
                    v = s * v;
                }
                Out[oidx] = f2bf(v);
            }
        }
    }
}

// ---------------- combine ----------------

__global__ __launch_bounds__(256) void combine_k(
    const unsigned short* __restrict__ Y, const int* __restrict__ rev,
    const float* __restrict__ gates, const int* __restrict__ gidx,
    float* __restrict__ out) {
    int t = blockIdx.x;
    int r0 = rev[2 * t], r1 = rev[2 * t + 1];
    float g0 = gates[gidx[2 * t]], g1 = gates[gidx[2 * t + 1]];
    const unsigned short* y0 = Y + (size_t)r0 * DDIM;
    const unsigned short* y1 = Y + (size_t)r1 * DDIM;
    int d = threadIdx.x * 4;
    ushort4 a = *(const ushort4*)(y0 + d);
    ushort4 b = *(const ushort4*)(y1 + d);
    float4 r;
    r.x = g0 * bf2f(a.x) + g1 * bf2f(b.x);
    r.y = g0 * bf2f(a.y) + g1 * bf2f(b.y);
    r.z = g0 * bf2f(a.z) + g1 * bf2f(b.z);
    r.w = g0 * bf2f(a.w) + g1 * bf2f(b.w);
    *(float4*)(out + (size_t)t * DDIM + d) = r;
}

// ---------------- launch ----------------

extern "C" void kernel_launch(void* const* d_in, const int* in_sizes, int n_in,
                              void* d_out, int out_size, void* d_ws, size_t ws_size,
                              hipStream_t stream) {
    const int* offsets = (const int*)d_in[0];
    const float* jagged = (const float*)d_in[1];
    const float* weight = (const float*)d_in[2];
    const float* bias = (const float*)d_in[3];
    const int* index = (const int*)d_in[4];
    const float* weight_p = (const float*)d_in[5];
    const float* weight_out = (const float*)d_in[6];
    const int* rev = (const int*)d_in[7];
    const float* gates = (const float*)d_in[8];
    const int* gidx = (const int*)d_in[9];
    const float* bias_p = (const float*)d_in[10];
    const float* bias_out = (const float*)d_in[11];
    float* out = (float*)d_out;

    char* w = (char*)d_ws;
    unsigned short* jag_bf = (unsigned short*)w; w += (size_t)T_TOK * DDIM * 2;       // 16MB
    unsigned short* W1t    = (unsigned short*)w; w += (size_t)NEXP * DDIM * HDIM * 2; // 16MB
    unsigned short* Wpt    = (unsigned short*)w; w += (size_t)NEXP * DDIM * HDIM * 2; // 16MB
    unsigned short* Wot    = (unsigned short*)w; w += (size_t)NEXP * HDIM * DDIM * 2; // 16MB
    unsigned short* g_ws   = (unsigned short*)w; w += (size_t)NROWS * HDIM * 2;       // 32MB
    unsigned short* h_ws   = (unsigned short*)w; w += (size_t)NROWS * HDIM * 2;       // 32MB
    unsigned short* y_ws   = g_ws;   // g dead after u-GEMM epilogue; reuse for y

    // prep: bf16 cast + weight transposes (B^T layout)
    cvt_bf16_k<<<(T_TOK * DDIM / 4 + 255) / 256, 256, 0, stream>>>(jagged, jag_bf, T_TOK * DDIM / 4);
    transpose_cast_k<<<dim3(HDIM / 32, DDIM / 32, NEXP), 256, 0, stream>>>(weight, W1t, DDIM, HDIM);
    transpose_cast_k<<<dim3(HDIM / 32, DDIM / 32, NEXP), 256, 0, stream>>>(weight_p, Wpt, DDIM, HDIM);
    transpose_cast_k<<<dim3(DDIM / 32, HDIM / 32, NEXP), 256, 0, stream>>>(weight_out, Wot, HDIM, DDIM);

    const int grid = (NROWS / BMk) * (HDIM / BNk);    // 128 * 8 = 1024 blocks

    // g = gather(x) @ W + b
    gemm128_k<0><<<grid, 256, 0, stream>>>(jag_bf, index, DDIM, W1t, bias, nullptr, g_ws,
                                           offsets, HDIM, DDIM);
    // h = silu(g) * (gather(x) @ Wp + bp)
    gemm128_k<1><<<grid, 256, 0, stream>>>(jag_bf, index, DDIM, Wpt, bias_p, g_ws, h_ws,
                                           offsets, HDIM, DDIM);
    // y = h @ Wout + bout
    gemm128_k<0><<<grid, 256, 0, stream>>>(h_ws, nullptr, HDIM, Wot, bias_out, nullptr, y_ws,
                                           offsets, DDIM, HDIM);
    // out[t] = sum_k gates[gidx[t,k]] * y[rev[t,k]]
    combine_k<<<T_TOK, 256, 0, stream>>>(y_ws, rev, gates, gidx, out);
}

// Round 14
// 173.339 us; speedup vs baseline: 1.0437x; 1.0388x over previous
//
#include <hip/hip_runtime.h>
#include <hip/hip_bf16.h>

#define T_TOK 8192
#define DDIM 1024
#define HDIM 1024
#define NEXP 8
#define KTOP 2
#define NROWS (T_TOK * KTOP)

typedef __attribute__((ext_vector_type(8))) short bf16x8;
typedef __attribute__((ext_vector_type(4))) float f32x4;

__device__ __forceinline__ unsigned short f2bf(float f) {
    unsigned u = __builtin_bit_cast(unsigned, f);
    u += 0x7fffu + ((u >> 16) & 1u);   // RNE
    return (unsigned short)(u >> 16);
}
__device__ __forceinline__ float bf2f(unsigned short h) {
    return __builtin_bit_cast(float, (unsigned)h << 16);
}

// async global->LDS, 16B per lane; LDS dest wave-uniform base + lane*16.
__device__ __forceinline__ void gll16(const unsigned short* g, const unsigned short* l) {
    __builtin_amdgcn_global_load_lds(
        (const __attribute__((address_space(1))) unsigned int*)g,
        (__attribute__((address_space(3))) unsigned int*)l, 16, 0, 0);
}

// ---------------- prep kernels ----------------

__global__ __launch_bounds__(256) void cvt_bf16_k(const float* __restrict__ in,
                                                  unsigned short* __restrict__ out, int n4) {
    int i = blockIdx.x * 256 + threadIdx.x;
    if (i >= n4) return;
    float4 v = ((const float4*)in)[i];
    ushort4 o;
    o.x = f2bf(v.x); o.y = f2bf(v.y); o.z = f2bf(v.z); o.w = f2bf(v.w);
    ((ushort4*)out)[i] = o;
}

// merged: z in [0,24): {weight, weight_p, weight_out}[z/8], expert z%8.
// in [1024][1024] f32 -> out [1024][1024]^T bf16.
__global__ __launch_bounds__(256) void transpose_cast3_k(
    const float* __restrict__ w1, const float* __restrict__ w2,
    const float* __restrict__ w3, unsigned short* __restrict__ o1,
    unsigned short* __restrict__ o2, unsigned short* __restrict__ o3) {
    __shared__ unsigned short tile[32][33];
    int z = blockIdx.z;
    int which = z >> 3, m = z & 7;
    const float* src = (which == 0 ? w1 : which == 1 ? w2 : w3) + (size_t)m * DDIM * HDIM;
    unsigned short* dst = (which == 0 ? o1 : which == 1 ? o2 : o3) + (size_t)m * DDIM * HDIM;
    int c0 = blockIdx.x * 32, r0 = blockIdx.y * 32;
    int tx = threadIdx.x & 31, ty = threadIdx.x >> 5;
#pragma unroll
    for (int i = 0; i < 32; i += 8)
        tile[ty + i][tx] = f2bf(src[(size_t)(r0 + ty + i) * HDIM + c0 + tx]);
    __syncthreads();
#pragma unroll
    for (int i = 0; i < 32; i += 8)
        dst[(size_t)(c0 + ty + i) * DDIM + r0 + tx] = tile[tx][ty + i];
}

// --------- 128x128 GEMM, m97-structure, single-buffer, 4 blocks/CU (block-TLP) --
// C = act(A @ Bt^T + bias). 256 thr = 4 waves (2x2), per-wave 64x64 out.
// BK=64, 16 K-iters, 32KB LDS single buffer, plain __syncthreads (compiler
// drains vmcnt/lgkm). Block-level TLP hides the per-tile drain (m114): r13
// proved 3 blocks/CU beats every 1-block/CU deep pipeline (45.2 vs 49-52us).
// This round: 4 blocks/CU (LDS 4x32=128KB <= 160; VGPR 60 <= 128@4w/SIMD).
// Swizzle: 16B chunk c of row r (128B line) stored at phys c^(r&7); gll16
// writes linear from inverse-swizzled global src; reads XOR the same
// (rule 21c) -> ~0 conflicts (involution verified r5-r13).
// T1: XCD-chunked map: 1024 blocks, XCD x owns brows [x*16,+16) = expert x.
// VARIANT 0: out = acc + bias ;  VARIANT 1: out = silu(Gin) * (acc + bias)

constexpr int BMk = 128, BNk = 128, BKk = 64;

template <int VARIANT>
__global__ __launch_bounds__(256, 4) void gemm128_k(
    const unsigned short* __restrict__ A, const int* __restrict__ rowidx, int lda,
    const unsigned short* __restrict__ Bt, const float* __restrict__ biasE,
    const unsigned short* __restrict__ Gin, unsigned short* __restrict__ Out,
    const int* __restrict__ offsets, int N, int K) {
    __shared__ __attribute__((aligned(16))) unsigned short lds[16384];  // 32 KiB

    const int nbn = N / BNk;                          // 8
    int l = (blockIdx.x & 7) * 128 + (blockIdx.x >> 3);
    int brow = l / nbn, bcol = l % nbn;
    int row0 = brow * BMk, col0 = bcol * BNk;
    int e = 0;
    while (offsets[e + 1] <= row0) ++e;

    const unsigned short* Bte = Bt + (size_t)e * N * K;
    const float* bias = biasE + (size_t)e * N;

    int tid = threadIdx.x;
    int lane = tid & 63, wid = tid >> 6;
    int wr = wid >> 1, wc = wid & 1;                  // 2x2 wave grid
    int l15 = lane & 15, l4 = lane >> 4;

    // staging: 16 A-groups + 16 B-groups of 1KB (8 rows x 128B); wave w owns
    // groups [w*4, +4). Inverse-swizzled per-lane global source.
    int srow = lane >> 3;
    int c8 = ((lane & 7) ^ srow) * 8;
    const unsigned short* aS[4];
    const unsigned short* bS[4];
#pragma unroll
    for (int q = 0; q < 4; ++q) {
        int g = wid * 4 + q;
        int gr = row0 + g * 8 + srow;
        int ar = rowidx ? rowidx[gr] : gr;
        aS[q] = A + (size_t)ar * lda + c8;
        bS[q] = Bte + (size_t)(col0 + g * 8 + srow) * K + c8;
    }

    // swizzled read offsets
    const char* LB = (const char*)lds;
    int arow = (wr * 64 + l15) * 128;                 // byte, within A tile
    int brw = (wc * 64 + l15) * 128;                  // byte, within B tile
    int cx = l15 & 7;
    int ch0 = (l4 ^ cx) * 16;
    int ch1 = ((4 + l4) ^ cx) * 16;

    f32x4 acc[4][4] = {};

#pragma unroll 1
    for (int t = 0; t < K / BKk; ++t) {
        int k0 = t * BKk;
#pragma unroll
        for (int q = 0; q < 4; ++q) {
            gll16(aS[q] + k0, lds + (wid * 4 + q) * 512);
            gll16(bS[q] + k0, lds + 8192 + (wid * 4 + q) * 512);
        }
        __syncthreads();   // drains vmcnt(0); co-resident blocks hide the wait
        bf16x8 fa[2][4], fb[2][4];
#pragma unroll
        for (int mi = 0; mi < 4; ++mi) {
            fa[0][mi] = *(const bf16x8*)(LB + arow + mi * 2048 + ch0);
            fa[1][mi] = *(const bf16x8*)(LB + arow + mi * 2048 + ch1);
        }
#pragma unroll
        for (int ni = 0; ni < 4; ++ni) {
            fb[0][ni] = *(const bf16x8*)(LB + 16384 + brw + ni * 2048 + ch0);
            fb[1][ni] = *(const bf16x8*)(LB + 16384 + brw + ni * 2048 + ch1);
        }
#pragma unroll
        for (int s = 0; s < 2; ++s)
#pragma unroll
            for (int mi = 0; mi < 4; ++mi)
#pragma unroll
                for (int ni = 0; ni < 4; ++ni)
                    acc[mi][ni] = __builtin_amdgcn_mfma_f32_16x16x32_bf16(
                        fa[s][mi], fb[s][ni], acc[mi][ni], 0, 0, 0);
        __syncthreads();   // reads done before next stage overwrites
    }

    float bv[4];
#pragma unroll
    for (int ni = 0; ni < 4; ++ni)
        bv[ni] = bias[col0 + wc * 64 + ni * 16 + l15];

#pragma unroll
    for (int mi = 0; mi < 4; ++mi) {
        int orow_b = row0 + wr * 64 + mi * 16 + l4 * 4;
#pragma unroll
        for (int ni = 0; ni < 4; ++ni) {
            int ocol = col0 + wc * 64 + ni * 16 + l15;
#pragma unroll
            for (int q = 0; q < 4; ++q) {
                size_t oidx = (size_t)(orow_b + q) * N + ocol;
                float v = acc[mi][ni][q] + bv[ni];
                if (VARIANT == 1) {
                    float g = bf2f(Gin[oidx]);
                    float s = g / (1.0f + __expf(-g));
                    v = s * v;
                }
                Out[oidx] = f2bf(v);
            }
        }
    }
}

// ---------------- combine ----------------

__global__ __launch_bounds__(256) void combine_k(
    const unsigned short* __restrict__ Y, const int* __restrict__ rev,
    const float* __restrict__ gates, const int* __restrict__ gidx,
    float* __restrict__ out) {
    int t = blockIdx.x;
    int r0 = rev[2 * t], r1 = rev[2 * t + 1];
    float g0 = gates[gidx[2 * t]], g1 = gates[gidx[2 * t + 1]];
    const unsigned short* y0 = Y + (size_t)r0 * DDIM;
    const unsigned short* y1 = Y + (size_t)r1 * DDIM;
    int d = threadIdx.x * 4;
    ushort4 a = *(const ushort4*)(y0 + d);
    ushort4 b = *(const ushort4*)(y1 + d);
    float4 r;
    r.x = g0 * bf2f(a.x) + g1 * bf2f(b.x);
    r.y = g0 * bf2f(a.y) + g1 * bf2f(b.y);
    r.z = g0 * bf2f(a.z) + g1 * bf2f(b.z);
    r.w = g0 * bf2f(a.w) + g1 * bf2f(b.w);
    *(float4*)(out + (size_t)t * DDIM + d) = r;
}

// ---------------- launch ----------------

extern "C" void kernel_launch(void* const* d_in, const int* in_sizes, int n_in,
                              void* d_out, int out_size, void* d_ws, size_t ws_size,
                              hipStream_t stream) {
    const int* offsets = (const int*)d_in[0];
    const float* jagged = (const float*)d_in[1];
    const float* weight = (const float*)d_in[2];
    const float* bias = (const float*)d_in[3];
    const int* index = (const int*)d_in[4];
    const float* weight_p = (const float*)d_in[5];
    const float* weight_out = (const float*)d_in[6];
    const int* rev = (const int*)d_in[7];
    const float* gates = (const float*)d_in[8];
    const int* gidx = (const int*)d_in[9];
    const float* bias_p = (const float*)d_in[10];
    const float* bias_out = (const float*)d_in[11];
    float* out = (float*)d_out;

    char* w = (char*)d_ws;
    unsigned short* jag_bf = (unsigned short*)w; w += (size_t)T_TOK * DDIM * 2;       // 16MB
    unsigned short* W1t    = (unsigned short*)w; w += (size_t)NEXP * DDIM * HDIM * 2; // 16MB
    unsigned short* Wpt    = (unsigned short*)w; w += (size_t)NEXP * DDIM * HDIM * 2; // 16MB
    unsigned short* Wot    = (unsigned short*)w; w += (size_t)NEXP * HDIM * DDIM * 2; // 16MB
    unsigned short* g_ws   = (unsigned short*)w; w += (size_t)NROWS * HDIM * 2;       // 32MB
    unsigned short* h_ws   = (unsigned short*)w; w += (size_t)NROWS * HDIM * 2;       // 32MB
    unsigned short* y_ws   = g_ws;   // g dead after u-GEMM epilogue; reuse for y

    // prep: bf16 cast + merged weight transposes (B^T layout, 1 dispatch)
    cvt_bf16_k<<<(T_TOK * DDIM / 4 + 255) / 256, 256, 0, stream>>>(jagged, jag_bf, T_TOK * DDIM / 4);
    transpose_cast3_k<<<dim3(HDIM / 32, DDIM / 32, 3 * NEXP), 256, 0, stream>>>(
        weight, weight_p, weight_out, W1t, Wpt, Wot);

    const int grid = (NROWS / BMk) * (HDIM / BNk);    // 128 * 8 = 1024 blocks

    // g = gather(x) @ W + b
    gemm128_k<0><<<grid, 256, 0, stream>>>(jag_bf, index, DDIM, W1t, bias, nullptr, g_ws,
                                           offsets, HDIM, DDIM);
    // h = silu(g) * (gather(x) @ Wp + bp)
    gemm128_k<1><<<grid, 256, 0, stream>>>(jag_bf, index, DDIM, Wpt, bias_p, g_ws, h_ws,
                                           offsets, HDIM, DDIM);
    // y = h @ Wout + bout
    gemm128_k<0><<<grid, 256, 0, stream>>>(h_ws, nullptr, HDIM, Wot, bias_out, nullptr, y_ws,
                                           offsets, DDIM, HDIM);
    // out[t] = sum_k gates[gidx[t,k]] * y[rev[t,k]]
    combine_k<<<T_TOK, 256, 0, stream>>>(y_ws, rev, gates, gidx, out);
}

// Round 15
// 171.706 us; speedup vs baseline: 1.0536x; 1.0095x over previous
//
#include <hip/hip_runtime.h>
#include <hip/hip_bf16.h>

#define T_TOK 8192
#define DDIM 1024
#define HDIM 1024
#define NEXP 8
#define KTOP 2
#define NROWS (T_TOK * KTOP)

typedef __attribute__((ext_vector_type(8))) short bf16x8;
typedef __attribute__((ext_vector_type(8))) unsigned short u16x8;
typedef __attribute__((ext_vector_type(4))) float f32x4;

__device__ __forceinline__ unsigned short f2bf(float f) {
    unsigned u = __builtin_bit_cast(unsigned, f);
    u += 0x7fffu + ((u >> 16) & 1u);   // RNE
    return (unsigned short)(u >> 16);
}
__device__ __forceinline__ float bf2f(unsigned short h) {
    return __builtin_bit_cast(float, (unsigned)h << 16);
}

// async global->LDS, 16B per lane; LDS dest wave-uniform base + lane*16.
__device__ __forceinline__ void gll16(const unsigned short* g, const unsigned short* l) {
    __builtin_amdgcn_global_load_lds(
        (const __attribute__((address_space(1))) unsigned int*)g,
        (__attribute__((address_space(3))) unsigned int*)l, 16, 0, 0);
}

// ---------------- prep kernels ----------------

__global__ __launch_bounds__(256) void cvt_bf16_k(const float* __restrict__ in,
                                                  unsigned short* __restrict__ out, int n4) {
    int i = blockIdx.x * 256 + threadIdx.x;
    if (i >= n4) return;
    float4 v = ((const float4*)in)[i];
    ushort4 o;
    o.x = f2bf(v.x); o.y = f2bf(v.y); o.z = f2bf(v.z); o.w = f2bf(v.w);
    ((ushort4*)out)[i] = o;
}

// merged transpose+cast, 64x64 tiles, 16B/lane coalesced writes.
// z in [0,24): {weight, weight_p, weight_out}[z/8], expert z%8.
// dst[c*1024 + r] = bf16(src[r*1024 + c]).
// Read: 4x float4 full-line row loads. LDS f32 [64][65] (+1 pad).
// Write: lane t gathers 8 column elems tile[(t&7)*8+j][t>>3 (+32q)]
// (banks = (8*(t&7)+j+(t>>3)) mod 32 -> 2 lanes/bank = free, m136),
// cvt, one ushort8 16B store; 8 lanes produce each 128B output line.
__global__ __launch_bounds__(256) void transpose_cast3_k(
    const float* __restrict__ w1, const float* __restrict__ w2,
    const float* __restrict__ w3, unsigned short* __restrict__ o1,
    unsigned short* __restrict__ o2, unsigned short* __restrict__ o3) {
    __shared__ float tile[64][65];
    int z = blockIdx.z;
    int which = z >> 3, m = z & 7;
    const float* src = (which == 0 ? w1 : which == 1 ? w2 : w3) + (size_t)m * DDIM * HDIM;
    unsigned short* dst = (which == 0 ? o1 : which == 1 ? o2 : o3) + (size_t)m * DDIM * HDIM;
    int c0 = blockIdx.x * 64, r0 = blockIdx.y * 64;
    int t = threadIdx.x;
    int rr = t >> 4;             // 0..15
    int cc = (t & 15) * 4;       // 0..60
#pragma unroll
    for (int p = 0; p < 4; ++p) {
        float4 v = *(const float4*)&src[(size_t)(r0 + rr + p * 16) * HDIM + c0 + cc];
        tile[rr + p * 16][cc]     = v.x;
        tile[rr + p * 16][cc + 1] = v.y;
        tile[rr + p * 16][cc + 2] = v.z;
        tile[rr + p * 16][cc + 3] = v.w;
    }
    __syncthreads();
    int rb = (t & 7) * 8;        // 0..56
    int oc = t >> 3;             // 0..31
#pragma unroll
    for (int q = 0; q < 2; ++q) {
        int c = oc + q * 32;
        u16x8 o;
#pragma unroll
        for (int j = 0; j < 8; ++j)
            o[j] = f2bf(tile[rb + j][c]);
        *(u16x8*)&dst[(size_t)(c0 + c) * DDIM + r0 + rb] = o;
    }
}

// --------- 128x128 GEMM, m97-structure, single-buffer, block-TLP (r13/r14) -----
// C = act(A @ Bt^T + bias). 256 thr = 4 waves (2x2), per-wave 64x64 out.
// BK=64, 16 K-iters, 32KB LDS single buffer, plain __syncthreads (compiler
// drains vmcnt/lgkm). Block-level TLP hides the per-tile drain (m114): r13
// proved 3 blocks/CU beats every 1-block/CU deep pipeline (45.2 vs 49-52us).
// r14 A/B: 4th block/CU = null (occupancy pinned ~29%); bounds kept at 4.
// Swizzle: 16B chunk c of row r (128B line) stored at phys c^(r&7); gll16
// writes linear from inverse-swizzled global src; reads XOR the same
// (rule 21c) -> ~0 conflicts (involution verified r5-r14).
// T1: XCD-chunked map: 1024 blocks, XCD x owns brows [x*16,+16) = expert x.
// VARIANT 0: out = acc + bias ;  VARIANT 1: out = silu(Gin) * (acc + bias)

constexpr int BMk = 128, BNk = 128, BKk = 64;

template <int VARIANT>
__global__ __launch_bounds__(256, 4) void gemm128_k(
    const unsigned short* __restrict__ A, const int* __restrict__ rowidx, int lda,
    const unsigned short* __restrict__ Bt, const float* __restrict__ biasE,
    const unsigned short* __restrict__ Gin, unsigned short* __restrict__ Out,
    const int* __restrict__ offsets, int N, int K) {
    __shared__ __attribute__((aligned(16))) unsigned short lds[16384];  // 32 KiB

    const int nbn = N / BNk;                          // 8
    int l = (blockIdx.x & 7) * 128 + (blockIdx.x >> 3);
    int brow = l / nbn, bcol = l % nbn;
    int row0 = brow * BMk, col0 = bcol * BNk;
    int e = 0;
    while (offsets[e + 1] <= row0) ++e;

    const unsigned short* Bte = Bt + (size_t)e * N * K;
    const float* bias = biasE + (size_t)e * N;

    int tid = threadIdx.x;
    int lane = tid & 63, wid = tid >> 6;
    int wr = wid >> 1, wc = wid & 1;                  // 2x2 wave grid
    int l15 = lane & 15, l4 = lane >> 4;

    // staging: 16 A-groups + 16 B-groups of 1KB (8 rows x 128B); wave w owns
    // groups [w*4, +4). Inverse-swizzled per-lane global source.
    int srow = lane >> 3;
    int c8 = ((lane & 7) ^ srow) * 8;
    const unsigned short* aS[4];
    const unsigned short* bS[4];
#pragma unroll
    for (int q = 0; q < 4; ++q) {
        int g = wid * 4 + q;
        int gr = row0 + g * 8 + srow;
        int ar = rowidx ? rowidx[gr] : gr;
        aS[q] = A + (size_t)ar * lda + c8;
        bS[q] = Bte + (size_t)(col0 + g * 8 + srow) * K + c8;
    }

    // swizzled read offsets
    const char* LB = (const char*)lds;
    int arow = (wr * 64 + l15) * 128;                 // byte, within A tile
    int brw = (wc * 64 + l15) * 128;                  // byte, within B tile
    int cx = l15 & 7;
    int ch0 = (l4 ^ cx) * 16;
    int ch1 = ((4 + l4) ^ cx) * 16;

    f32x4 acc[4][4] = {};

#pragma unroll 1
    for (int t = 0; t < K / BKk; ++t) {
        int k0 = t * BKk;
#pragma unroll
        for (int q = 0; q < 4; ++q) {
            gll16(aS[q] + k0, lds + (wid * 4 + q) * 512);
            gll16(bS[q] + k0, lds + 8192 + (wid * 4 + q) * 512);
        }
        __syncthreads();   // drains vmcnt(0); co-resident blocks hide the wait
        bf16x8 fa[2][4], fb[2][4];
#pragma unroll
        for (int mi = 0; mi < 4; ++mi) {
            fa[0][mi] = *(const bf16x8*)(LB + arow + mi * 2048 + ch0);
            fa[1][mi] = *(const bf16x8*)(LB + arow + mi * 2048 + ch1);
        }
#pragma unroll
        for (int ni = 0; ni < 4; ++ni) {
            fb[0][ni] = *(const bf16x8*)(LB + 16384 + brw + ni * 2048 + ch0);
            fb[1][ni] = *(const bf16x8*)(LB + 16384 + brw + ni * 2048 + ch1);
        }
#pragma unroll
        for (int s = 0; s < 2; ++s)
#pragma unroll
            for (int mi = 0; mi < 4; ++mi)
#pragma unroll
                for (int ni = 0; ni < 4; ++ni)
                    acc[mi][ni] = __builtin_amdgcn_mfma_f32_16x16x32_bf16(
                        fa[s][mi], fb[s][ni], acc[mi][ni], 0, 0, 0);
        __syncthreads();   // reads done before next stage overwrites
    }

    float bv[4];
#pragma unroll
    for (int ni = 0; ni < 4; ++ni)
        bv[ni] = bias[col0 + wc * 64 + ni * 16 + l15];

#pragma unroll
    for (int mi = 0; mi < 4; ++mi) {
        int orow_b = row0 + wr * 64 + mi * 16 + l4 * 4;
#pragma unroll
        for (int ni = 0; ni < 4; ++ni) {
            int ocol = col0 + wc * 64 + ni * 16 + l15;
#pragma unroll
            for (int q = 0; q < 4; ++q) {
                size_t oidx = (size_t)(orow_b + q) * N + ocol;
                float v = acc[mi][ni][q] + bv[ni];
                if (VARIANT == 1) {
                    float g = bf2f(Gin[oidx]);
                    float s = g / (1.0f + __expf(-g));
                    v = s * v;
                }
                Out[oidx] = f2bf(v);
            }
        }
    }
}

// ---------------- combine ----------------

__global__ __launch_bounds__(256) void combine_k(
    const unsigned short* __restrict__ Y, const int* __restrict__ rev,
    const float* __restrict__ gates, const int* __restrict__ gidx,
    float* __restrict__ out) {
    int t = blockIdx.x;
    int r0 = rev[2 * t], r1 = rev[2 * t + 1];
    float g0 = gates[gidx[2 * t]], g1 = gates[gidx[2 * t + 1]];
    const unsigned short* y0 = Y + (size_t)r0 * DDIM;
    const unsigned short* y1 = Y + (size_t)r1 * DDIM;
    int d = threadIdx.x * 4;
    ushort4 a = *(const ushort4*)(y0 + d);
    ushort4 b = *(const ushort4*)(y1 + d);
    float4 r;
    r.x = g0 * bf2f(a.x) + g1 * bf2f(b.x);
    r.y = g0 * bf2f(a.y) + g1 * bf2f(b.y);
    r.z = g0 * bf2f(a.z) + g1 * bf2f(b.z);
    r.w = g0 * bf2f(a.w) + g1 * bf2f(b.w);
    *(float4*)(out + (size_t)t * DDIM + d) = r;
}

// ---------------- launch ----------------

extern "C" void kernel_launch(void* const* d_in, const int* in_sizes, int n_in,
                              void* d_out, int out_size, void* d_ws, size_t ws_size,
                              hipStream_t stream) {
    const int* offsets = (const int*)d_in[0];
    const float* jagged = (const float*)d_in[1];
    const float* weight = (const float*)d_in[2];
    const float* bias = (const float*)d_in[3];
    const int* index = (const int*)d_in[4];
    const float* weight_p = (const float*)d_in[5];
    const float* weight_out = (const float*)d_in[6];
    const int* rev = (const int*)d_in[7];
    const float* gates = (const float*)d_in[8];
    const int* gidx = (const int*)d_in[9];
    const float* bias_p = (const float*)d_in[10];
    const float* bias_out = (const float*)d_in[11];
    float* out = (float*)d_out;

    char* w = (char*)d_ws;
    unsigned short* jag_bf = (unsigned short*)w; w += (size_t)T_TOK * DDIM * 2;       // 16MB
    unsigned short* W1t    = (unsigned short*)w; w += (size_t)NEXP * DDIM * HDIM * 2; // 16MB
    unsigned short* Wpt    = (unsigned short*)w; w += (size_t)NEXP * DDIM * HDIM * 2; // 16MB
    unsigned short* Wot    = (unsigned short*)w; w += (size_t)NEXP * HDIM * DDIM * 2; // 16MB
    unsigned short* g_ws   = (unsigned short*)w; w += (size_t)NROWS * HDIM * 2;       // 32MB
    unsigned short* h_ws   = (unsigned short*)w; w += (size_t)NROWS * HDIM * 2;       // 32MB
    unsigned short* y_ws   = g_ws;   // g dead after u-GEMM epilogue; reuse for y

    // prep: bf16 cast + merged weight transposes (B^T layout, 1 dispatch)
    cvt_bf16_k<<<(T_TOK * DDIM / 4 + 255) / 256, 256, 0, stream>>>(jagged, jag_bf, T_TOK * DDIM / 4);
    transpose_cast3_k<<<dim3(HDIM / 64, DDIM / 64, 3 * NEXP), 256, 0, stream>>>(
        weight, weight_p, weight_out, W1t, Wpt, Wot);

    const int grid = (NROWS / BMk) * (HDIM / BNk);    // 128 * 8 = 1024 blocks

    // g = gather(x) @ W + b
    gemm128_k<0><<<grid, 256, 0, stream>>>(jag_bf, index, DDIM, W1t, bias, nullptr, g_ws,
                                           offsets, HDIM, DDIM);
    // h = silu(g) * (gather(x) @ Wp + bp)
    gemm128_k<1><<<grid, 256, 0, stream>>>(jag_bf, index, DDIM, Wpt, bias_p, g_ws, h_ws,
                                           offsets, HDIM, DDIM);
    // y = h @ Wout + bout
    gemm128_k<0><<<grid, 256, 0, stream>>>(h_ws, nullptr, HDIM, Wot, bias_out, nullptr, y_ws,
                                           offsets, DDIM, HDIM);
    // out[t] = sum_k gates[gidx[t,k]] * y[rev[t,k]]
    combine_k<<<T_TOK, 256, 0, stream>>>(y_ws, rev, gates, gidx, out);
}

// Round 16
// 166.496 us; speedup vs baseline: 1.0866x; 1.0313x over previous
//
#include <hip/hip_runtime.h>
#include <hip/hip_bf16.h>

#define T_TOK 8192
#define DDIM 1024
#define HDIM 1024
#define NEXP 8
#define KTOP 2
#define NROWS (T_TOK * KTOP)

typedef __attribute__((ext_vector_type(8))) short bf16x8;
typedef __attribute__((ext_vector_type(8))) unsigned short u16x8;
typedef __attribute__((ext_vector_type(4))) float f32x4;

__device__ __forceinline__ unsigned short f2bf(float f) {
    unsigned u = __builtin_bit_cast(unsigned, f);
    u += 0x7fffu + ((u >> 16) & 1u);   // RNE
    return (unsigned short)(u >> 16);
}
__device__ __forceinline__ float bf2f(unsigned short h) {
    return __builtin_bit_cast(float, (unsigned)h << 16);
}

// async global->LDS, 16B per lane; LDS dest wave-uniform base + lane*16.
__device__ __forceinline__ void gll16(const unsigned short* g, const unsigned short* l) {
    __builtin_amdgcn_global_load_lds(
        (const __attribute__((address_space(1))) unsigned int*)g,
        (__attribute__((address_space(3))) unsigned int*)l, 16, 0, 0);
}

// ---------------- prep kernels ----------------

__global__ __launch_bounds__(256) void cvt_bf16_k(const float* __restrict__ in,
                                                  unsigned short* __restrict__ out, int n4) {
    int i = blockIdx.x * 256 + threadIdx.x;
    if (i >= n4) return;
    float4 v = ((const float4*)in)[i];
    ushort4 o;
    o.x = f2bf(v.x); o.y = f2bf(v.y); o.z = f2bf(v.z); o.w = f2bf(v.w);
    ((ushort4*)out)[i] = o;
}

// merged transpose+cast, 64x64 tiles, 16B/lane coalesced writes (r15, verified).
__global__ __launch_bounds__(256) void transpose_cast3_k(
    const float* __restrict__ w1, const float* __restrict__ w2,
    const float* __restrict__ w3, unsigned short* __restrict__ o1,
    unsigned short* __restrict__ o2, unsigned short* __restrict__ o3) {
    __shared__ float tile[64][65];
    int z = blockIdx.z;
    int which = z >> 3, m = z & 7;
    const float* src = (which == 0 ? w1 : which == 1 ? w2 : w3) + (size_t)m * DDIM * HDIM;
    unsigned short* dst = (which == 0 ? o1 : which == 1 ? o2 : o3) + (size_t)m * DDIM * HDIM;
    int c0 = blockIdx.x * 64, r0 = blockIdx.y * 64;
    int t = threadIdx.x;
    int rr = t >> 4;
    int cc = (t & 15) * 4;
#pragma unroll
    for (int p = 0; p < 4; ++p) {
        float4 v = *(const float4*)&src[(size_t)(r0 + rr + p * 16) * HDIM + c0 + cc];
        tile[rr + p * 16][cc]     = v.x;
        tile[rr + p * 16][cc + 1] = v.y;
        tile[rr + p * 16][cc + 2] = v.z;
        tile[rr + p * 16][cc + 3] = v.w;
    }
    __syncthreads();
    int rb = (t & 7) * 8;
    int oc = t >> 3;
#pragma unroll
    for (int q = 0; q < 2; ++q) {
        int c = oc + q * 32;
        u16x8 o;
#pragma unroll
        for (int j = 0; j < 8; ++j)
            o[j] = f2bf(tile[rb + j][c]);
        *(u16x8*)&dst[(size_t)(c0 + c) * DDIM + r0 + rb] = o;
    }
}

// --- 128x256 GEMM, wave=64x128 out: LDS-traffic-optimized (0.375 reads/MFMA) ---
// MODEL (r16): r13's 128x128 was LDS-BW-bound: per CU per K-iter, MFMA needs
// ~2480cyc but LDS (frag reads 0.5/MFMA + gll16 writes) needs ~4500cyc at
// 85B/cyc (m134). Fix = fragment reuse, not scheduling: per-wave 64x128 output
// -> 24 frag reads per 64 MFMA (0.375) and per-CU LDS bytes/iter 384->288KB
// while MFMA/iter doubles. Retro-fits r11 (0.75 ratio, 49us) > r13 (0.5, 45us).
// Geometry: 256 thr = 4 waves (2x2: wm in {0,1} rows, wn in {0,1} cols of 128).
// BK=64, 16 K-iters, LDS 48KB single-buffered (A 16KB + B 32KB), grid 512 =
// 2 blocks/CU (VGPR ~200 caps at 2 anyway). Plain __syncthreads (r13's winner).
// Swizzle (verified r5-r15): 16B chunk c of 128B row r at phys c^(r&7); gll16
// linear dest + inverse-swizzled global src; reads XOR same -> ~0 conflicts.
// T1: XCD-chunked: 512 blocks, 64/XCD = expert x's 16x4 tile grid exactly.
// VARIANT 0: out = acc + bias ;  VARIANT 1: out = silu(Gin) * (acc + bias)

constexpr int BMk = 128, BNk = 256, BKk = 64;

template <int VARIANT>
__global__ __launch_bounds__(256, 2) void gemm128x256_k(
    const unsigned short* __restrict__ A, const int* __restrict__ rowidx, int lda,
    const unsigned short* __restrict__ Bt, const float* __restrict__ biasE,
    const unsigned short* __restrict__ Gin, unsigned short* __restrict__ Out,
    const int* __restrict__ offsets, int N, int K) {
    __shared__ __attribute__((aligned(16))) unsigned short lds[24576];  // 48 KiB

    const int nbn = N / BNk;                          // 4
    int l = (blockIdx.x & 7) * 64 + (blockIdx.x >> 3);
    int brow = l / nbn, bcol = l % nbn;
    int row0 = brow * BMk, col0 = bcol * BNk;
    int e = 0;
    while (offsets[e + 1] <= row0) ++e;

    const unsigned short* Bte = Bt + (size_t)e * N * K;
    const float* bias = biasE + (size_t)e * N;

    int tid = threadIdx.x;
    int lane = tid & 63, wid = tid >> 6;
    int wm = wid >> 1, wn = wid & 1;                  // 2x2; wave = 64 rows x 128 cols
    int l15 = lane & 15, l4 = lane >> 4;

    // staging: A = 16 groups (1KB = 8 rows x 128B), wave owns [wid*4,+4);
    //          B = 32 groups, wave owns [wid*8,+8). Inverse-swizzled source.
    int srow = lane >> 3;
    int c8 = ((lane & 7) ^ srow) * 8;
    const unsigned short* aS[4];
    const unsigned short* bS[8];
#pragma unroll
    for (int q = 0; q < 4; ++q) {
        int gr = row0 + (wid * 4 + q) * 8 + srow;
        int ar = rowidx ? rowidx[gr] : gr;
        aS[q] = A + (size_t)ar * lda + c8;
    }
#pragma unroll
    for (int q = 0; q < 8; ++q)
        bS[q] = Bte + (size_t)(col0 + (wid * 8 + q) * 8 + srow) * K + c8;

    // swizzled read offsets
    const char* LB = (const char*)lds;
    int arow = (wm * 64 + l15) * 128;                 // byte, within A (16KB)
    int brw = (wn * 128 + l15) * 128;                 // byte, within B (32KB)
    int cx = l15 & 7;
    int ch0 = (l4 ^ cx) * 16;
    int ch1 = ((4 + l4) ^ cx) * 16;

    f32x4 acc[4][8] = {};

#pragma unroll 1
    for (int t = 0; t < K / BKk; ++t) {
        int k0 = t * BKk;
#pragma unroll
        for (int q = 0; q < 4; ++q)
            gll16(aS[q] + k0, lds + (wid * 4 + q) * 512);
#pragma unroll
        for (int q = 0; q < 8; ++q)
            gll16(bS[q] + k0, lds + 8192 + (wid * 8 + q) * 512);
        __syncthreads();   // drains vmcnt(0); other block + waves hide the wait
        {   // k-slice 0
            bf16x8 fa[4], fb[8];
#pragma unroll
            for (int mi = 0; mi < 4; ++mi)
                fa[mi] = *(const bf16x8*)(LB + arow + mi * 2048 + ch0);
#pragma unroll
            for (int ni = 0; ni < 8; ++ni)
                fb[ni] = *(const bf16x8*)(LB + 16384 + brw + ni * 2048 + ch0);
#pragma unroll
            for (int mi = 0; mi < 4; ++mi)
#pragma unroll
                for (int ni = 0; ni < 8; ++ni)
                    acc[mi][ni] = __builtin_amdgcn_mfma_f32_16x16x32_bf16(
                        fa[mi], fb[ni], acc[mi][ni], 0, 0, 0);
        }
        {   // k-slice 1
            bf16x8 fa[4], fb[8];
#pragma unroll
            for (int mi = 0; mi < 4; ++mi)
                fa[mi] = *(const bf16x8*)(LB + arow + mi * 2048 + ch1);
#pragma unroll
            for (int ni = 0; ni < 8; ++ni)
                fb[ni] = *(const bf16x8*)(LB + 16384 + brw + ni * 2048 + ch1);
#pragma unroll
            for (int mi = 0; mi < 4; ++mi)
#pragma unroll
                for (int ni = 0; ni < 8; ++ni)
                    acc[mi][ni] = __builtin_amdgcn_mfma_f32_16x16x32_bf16(
                        fa[mi], fb[ni], acc[mi][ni], 0, 0, 0);
        }
        __syncthreads();   // reads done before next stage overwrites
    }

    float bv[8];
#pragma unroll
    for (int ni = 0; ni < 8; ++ni)
        bv[ni] = bias[col0 + wn * 128 + ni * 16 + l15];

#pragma unroll
    for (int mi = 0; mi < 4; ++mi) {
        int orow_b = row0 + wm * 64 + mi * 16 + l4 * 4;
#pragma unroll
        for (int ni = 0; ni < 8; ++ni) {
            int ocol = col0 + wn * 128 + ni * 16 + l15;
#pragma unroll
            for (int q = 0; q < 4; ++q) {
                size_t oidx = (size_t)(orow_b + q) * N + ocol;
                float v = acc[mi][ni][q] + bv[ni];
                if (VARIANT == 1) {
                    float g = bf2f(Gin[oidx]);
                    float s = g / (1.0f + __expf(-g));
                    v = s * v;
                }
                Out[oidx] = f2bf(v);
            }
        }
    }
}

// ---------------- combine ----------------

__global__ __launch_bounds__(256) void combine_k(
    const unsigned short* __restrict__ Y, const int* __restrict__ rev,
    const float* __restrict__ gates, const int* __restrict__ gidx,
    float* __restrict__ out) {
    int t = blockIdx.x;
    int r0 = rev[2 * t], r1 = rev[2 * t + 1];
    float g0 = gates[gidx[2 * t]], g1 = gates[gidx[2 * t + 1]];
    const unsigned short* y0 = Y + (size_t)r0 * DDIM;
    const unsigned short* y1 = Y + (size_t)r1 * DDIM;
    int d = threadIdx.x * 4;
    ushort4 a = *(const ushort4*)(y0 + d);
    ushort4 b = *(const ushort4*)(y1 + d);
    float4 r;
    r.x = g0 * bf2f(a.x) + g1 * bf2f(b.x);
    r.y = g0 * bf2f(a.y) + g1 * bf2f(b.y);
    r.z = g0 * bf2f(a.z) + g1 * bf2f(b.z);
    r.w = g0 * bf2f(a.w) + g1 * bf2f(b.w);
    *(float4*)(out + (size_t)t * DDIM + d) = r;
}

// ---------------- launch ----------------

extern "C" void kernel_launch(void* const* d_in, const int* in_sizes, int n_in,
                              void* d_out, int out_size, void* d_ws, size_t ws_size,
                              hipStream_t stream) {
    const int* offsets = (const int*)d_in[0];
    const float* jagged = (const float*)d_in[1];
    const float* weight = (const float*)d_in[2];
    const float* bias = (const float*)d_in[3];
    const int* index = (const int*)d_in[4];
    const float* weight_p = (const float*)d_in[5];
    const float* weight_out = (const float*)d_in[6];
    const int* rev = (const int*)d_in[7];
    const float* gates = (const float*)d_in[8];
    const int* gidx = (const int*)d_in[9];
    const float* bias_p = (const float*)d_in[10];
    const float* bias_out = (const float*)d_in[11];
    float* out = (float*)d_out;

    char* w = (char*)d_ws;
    unsigned short* jag_bf = (unsigned short*)w; w += (size_t)T_TOK * DDIM * 2;       // 16MB
    unsigned short* W1t    = (unsigned short*)w; w += (size_t)NEXP * DDIM * HDIM * 2; // 16MB
    unsigned short* Wpt    = (unsigned short*)w; w += (size_t)NEXP * DDIM * HDIM * 2; // 16MB
    unsigned short* Wot    = (unsigned short*)w; w += (size_t)NEXP * HDIM * DDIM * 2; // 16MB
    unsigned short* g_ws   = (unsigned short*)w; w += (size_t)NROWS * HDIM * 2;       // 32MB
    unsigned short* h_ws   = (unsigned short*)w; w += (size_t)NROWS * HDIM * 2;       // 32MB
    unsigned short* y_ws   = g_ws;   // g dead after u-GEMM epilogue; reuse for y

    // prep: bf16 cast + merged weight transposes (B^T layout, 1 dispatch)
    cvt_bf16_k<<<(T_TOK * DDIM / 4 + 255) / 256, 256, 0, stream>>>(jagged, jag_bf, T_TOK * DDIM / 4);
    transpose_cast3_k<<<dim3(HDIM / 64, DDIM / 64, 3 * NEXP), 256, 0, stream>>>(
        weight, weight_p, weight_out, W1t, Wpt, Wot);

    const int grid = (NROWS / BMk) * (HDIM / BNk);    // 128 * 4 = 512 blocks

    // g = gather(x) @ W + b
    gemm128x256_k<0><<<grid, 256, 0, stream>>>(jag_bf, index, DDIM, W1t, bias, nullptr, g_ws,
                                               offsets, HDIM, DDIM);
    // h = silu(g) * (gather(x) @ Wp + bp)
    gemm128x256_k<1><<<grid, 256, 0, stream>>>(jag_bf, index, DDIM, Wpt, bias_p, g_ws, h_ws,
                                               offsets, HDIM, DDIM);
    // y = h @ Wout + bout
    gemm128x256_k<0><<<grid, 256, 0, stream>>>(h_ws, nullptr, HDIM, Wot, bias_out, nullptr, y_ws,
                                               offsets, DDIM, HDIM);
    // out[t] = sum_k gates[gidx[t,k]] * y[rev[t,k]]
    combine_k<<<T_TOK, 256, 0, stream>>>(y_ws, rev, gates, gidx, out);
}